// Round 1
// baseline (609.177 us; speedup 1.0000x reference)
//
#include <hip/hip_runtime.h>
#include <hip/hip_bf16.h>

// GCN: x1=relu(prop(x W1)), x2=relu(prop(x1 W2)), x3=prop(x2 W3)
// out(fp32) = [emb (N x 192), colmax(emb) (192), emb[target] @ fcW + fcb (4)]
// R7 (base=R6):
//  - k_fill_gemm1: __launch_bounds__(256,4) caps VGPR<=128 (was 248, occ 9.5%);
//    fill role now 8 independent atomic+store chains/thread (was 4)
//  - k_aggregate: 16 lanes/node, ushort4 (8B) gathers -> one wave covers 4 nodes
//    per gather instruction (~4x fewer gather instrs vs 64-lane/node 2B loads)

#define ELL_CAP 64

__device__ __forceinline__ float bfu(unsigned short s) {
    return __uint_as_float(((unsigned)s) << 16);
}
__device__ __forceinline__ unsigned short f2bfu(float f) {
    __hip_bfloat16 b = __float2bfloat16(f);
    return *reinterpret_cast<unsigned short*>(&b);
}

// ---- fused: ELL fill (blocks [0,FB)) + gemm1 g=x@W1 (blocks [FB,FB+GB)) ---
__global__ __launch_bounds__(256, 4) void k_fill_gemm1(
    const int* __restrict__ src, const int* __restrict__ dst,
    int* __restrict__ cnt, unsigned short* __restrict__ col, int E, int FB,
    const float* __restrict__ X, const float* __restrict__ W,
    unsigned short* __restrict__ g, int N) {
    int t = threadIdx.x;
    if ((int)blockIdx.x < FB) {
        // ---- fill role: 8 edges per thread, independent chains ----
        int e0 = blockIdx.x * 2048 + t;
        #pragma unroll
        for (int i = 0; i < 8; ++i) {
            int e = e0 + i * 256;
            if (e < E) {
                int d = dst[e];
                int s = src[e];
                int slot = atomicAdd(&cnt[d], 1);
                if (slot < ELL_CAP) col[((size_t)d << 6) + slot] = (unsigned short)s;
            }
        }
        return;
    }
    // ---- gemm role: 64x64 tile, g = bf16(x @ W1)  (no dinv yet) ----
    __shared__ float Xs[64 * 68];
    __shared__ float Ws[64 * 68];
    int row0 = (blockIdx.x - FB) * 64;
    #pragma unroll
    for (int i = 0; i < 4; ++i) {
        int f = t + i * 256;
        int k = f >> 4, cq = (f & 15) << 2;
        float4 wv = *(const float4*)(W + k * 64 + cq);
        Ws[k * 68 + cq + 0] = wv.x;
        Ws[k * 68 + cq + 1] = wv.y;
        Ws[k * 68 + cq + 2] = wv.z;
        Ws[k * 68 + cq + 3] = wv.w;
        int r = f >> 4, kq = (f & 15) << 2;
        int row = row0 + r;
        float4 xv = make_float4(0.f, 0.f, 0.f, 0.f);
        if (row < N) xv = *(const float4*)(X + (size_t)row * 64 + kq);
        Xs[(kq + 0) * 68 + r] = xv.x;
        Xs[(kq + 1) * 68 + r] = xv.y;
        Xs[(kq + 2) * 68 + r] = xv.z;
        Xs[(kq + 3) * 68 + r] = xv.w;
    }
    __syncthreads();
    int tx = t & 15, ty = t >> 4;
    float acc[4][4] = {};
    #pragma unroll
    for (int k = 0; k < 64; ++k) {
        float4 a = *(const float4*)&Xs[k * 68 + ty * 4];
        float4 b = *(const float4*)&Ws[k * 68 + tx * 4];
        float av[4] = {a.x, a.y, a.z, a.w};
        float bv[4] = {b.x, b.y, b.z, b.w};
        #pragma unroll
        for (int i = 0; i < 4; ++i)
            #pragma unroll
            for (int j = 0; j < 4; ++j) acc[i][j] += av[i] * bv[j];
    }
    #pragma unroll
    for (int i = 0; i < 4; ++i) {
        int row = row0 + ty * 4 + i;
        if (row < N) {
            ushort4 o;
            o.x = f2bfu(acc[i][0]);
            o.y = f2bfu(acc[i][1]);
            o.z = f2bfu(acc[i][2]);
            o.w = f2bfu(acc[i][3]);
            *(ushort4*)(g + (size_t)row * 64 + tx * 4) = o;
        }
    }
}

// ---- scale: dinv[r] = rsqrt(cnt+1); g[r][:] *= dinv[r] --------------------
__global__ __launch_bounds__(256) void k_scale(const int* __restrict__ cnt,
                                               float* __restrict__ dinv,
                                               unsigned short* __restrict__ g, int N) {
    int idx = blockIdx.x * blockDim.x + threadIdx.x;  // one ushort4 (4 chans)
    if (idx >= N * 16) return;
    int r = idx >> 4;
    float d = rsqrtf((float)(cnt[r] + 1));  // +1 self-loop
    if ((idx & 15) == 0) dinv[r] = d;
    ushort4 v = *(ushort4*)(g + (size_t)idx * 4);
    v.x = f2bfu(bfu(v.x) * d);
    v.y = f2bfu(bfu(v.y) * d);
    v.z = f2bfu(bfu(v.z) * d);
    v.w = f2bfu(bfu(v.w) * d);
    *(ushort4*)(g + (size_t)idx * 4) = v;
}

// ---- g = bf16(dinv * (X @ W)); layers 2,3 (X fp32, row stride xstride) ----
__global__ __launch_bounds__(256) void k_gemm_g(const float* __restrict__ X,
                                                int xstride,
                                                const float* __restrict__ W,
                                                const float* __restrict__ dinv,
                                                unsigned short* __restrict__ g, int N) {
    __shared__ float Xs[64 * 68];
    __shared__ float Ws[64 * 68];
    int t = threadIdx.x;
    int row0 = blockIdx.x * 64;
    #pragma unroll
    for (int i = 0; i < 4; ++i) {
        int f = t + i * 256;
        int k = f >> 4, cq = (f & 15) << 2;
        float4 wv = *(const float4*)(W + k * 64 + cq);
        Ws[k * 68 + cq + 0] = wv.x;
        Ws[k * 68 + cq + 1] = wv.y;
        Ws[k * 68 + cq + 2] = wv.z;
        Ws[k * 68 + cq + 3] = wv.w;
        int r = f >> 4, kq = (f & 15) << 2;
        int row = row0 + r;
        float4 xv = make_float4(0.f, 0.f, 0.f, 0.f);
        if (row < N) xv = *(const float4*)(X + (size_t)row * xstride + kq);
        Xs[(kq + 0) * 68 + r] = xv.x;
        Xs[(kq + 1) * 68 + r] = xv.y;
        Xs[(kq + 2) * 68 + r] = xv.z;
        Xs[(kq + 3) * 68 + r] = xv.w;
    }
    __syncthreads();
    int tx = t & 15, ty = t >> 4;
    float acc[4][4] = {};
    #pragma unroll
    for (int k = 0; k < 64; ++k) {
        float4 a = *(const float4*)&Xs[k * 68 + ty * 4];
        float4 b = *(const float4*)&Ws[k * 68 + tx * 4];
        float av[4] = {a.x, a.y, a.z, a.w};
        float bv[4] = {b.x, b.y, b.z, b.w};
        #pragma unroll
        for (int i = 0; i < 4; ++i)
            #pragma unroll
            for (int j = 0; j < 4; ++j) acc[i][j] += av[i] * bv[j];
    }
    #pragma unroll
    for (int i = 0; i < 4; ++i) {
        int row = row0 + ty * 4 + i;
        if (row < N) {
            float dv = dinv[row];
            ushort4 o;
            o.x = f2bfu(acc[i][0] * dv);
            o.y = f2bfu(acc[i][1] * dv);
            o.z = f2bfu(acc[i][2] * dv);
            o.w = f2bfu(acc[i][3] * dv);
            *(ushort4*)(g + (size_t)row * 64 + tx * 4) = o;
        }
    }
}

// 16 lanes per node, each lane owns 4 channels (ushort4 = 8B loads).
// One wave = 4 nodes -> each gather instruction covers 4 edges.
__global__ __launch_bounds__(256) void k_aggregate(
    const unsigned short* __restrict__ g, const float* __restrict__ dinv,
    const int* __restrict__ cnt, const unsigned short* __restrict__ col,
    const float* __restrict__ bias,
    float* __restrict__ outp, int relu, int N) {
    int gid = blockIdx.x * blockDim.x + threadIdx.x;
    int node = gid >> 4;
    int l = gid & 15;           // channels 4l .. 4l+3
    if (node >= N) return;
    ushort4 sv = *(const ushort4*)(g + ((size_t)node << 6) + (l << 2));
    float a0 = bfu(sv.x), a1 = bfu(sv.y), a2 = bfu(sv.z), a3 = bfu(sv.w);
    int deg = cnt[node];
    int m = deg < ELL_CAP ? deg : ELL_CAP;
    const unsigned short* crow = col + ((size_t)node << 6);
    int e = 0;
    for (; e + 3 < m; e += 4) {
        ushort4 s4 = *(const ushort4*)(crow + e);   // uniform in 16-group -> bcast
        ushort4 v0 = *(const ushort4*)(g + ((size_t)s4.x << 6) + (l << 2));
        ushort4 v1 = *(const ushort4*)(g + ((size_t)s4.y << 6) + (l << 2));
        ushort4 v2 = *(const ushort4*)(g + ((size_t)s4.z << 6) + (l << 2));
        ushort4 v3 = *(const ushort4*)(g + ((size_t)s4.w << 6) + (l << 2));
        a0 += (bfu(v0.x) + bfu(v1.x)) + (bfu(v2.x) + bfu(v3.x));
        a1 += (bfu(v0.y) + bfu(v1.y)) + (bfu(v2.y) + bfu(v3.y));
        a2 += (bfu(v0.z) + bfu(v1.z)) + (bfu(v2.z) + bfu(v3.z));
        a3 += (bfu(v0.w) + bfu(v1.w)) + (bfu(v2.w) + bfu(v3.w));
    }
    for (; e < m; ++e) {
        int s = crow[e];
        ushort4 v = *(const ushort4*)(g + ((size_t)s << 6) + (l << 2));
        a0 += bfu(v.x);
        a1 += bfu(v.y);
        a2 += bfu(v.z);
        a3 += bfu(v.w);
    }
    float d = dinv[node];
    float4 bv = *(const float4*)(bias + (l << 2));
    float4 o;
    o.x = fmaf(d, a0, bv.x);
    o.y = fmaf(d, a1, bv.y);
    o.z = fmaf(d, a2, bv.z);
    o.w = fmaf(d, a3, bv.w);
    if (relu) {
        o.x = fmaxf(o.x, 0.0f);
        o.y = fmaxf(o.y, 0.0f);
        o.z = fmaxf(o.z, 0.0f);
        o.w = fmaxf(o.w, 0.0f);
    }
    *(float4*)(outp + (size_t)node * 192 + (l << 2)) = o;
}

// ---- epilogue -------------------------------------------------------------
__global__ __launch_bounds__(192) void k_colmax(const float* __restrict__ emb,
                                                unsigned int* __restrict__ menc, int N) {
    int c = threadIdx.x;
    float m = -3.4e38f;
    for (int r = blockIdx.x; r < N; r += gridDim.x)
        m = fmaxf(m, emb[(size_t)r * 192 + c]);
    unsigned int b = __float_as_uint(m);
    unsigned int enc = (b & 0x80000000u) ? ~b : (b | 0x80000000u);
    atomicMax(&menc[c], enc);
}

__global__ __launch_bounds__(256) void k_final(const unsigned int* __restrict__ menc,
                                               const float* __restrict__ emb,
                                               const int* __restrict__ target,
                                               const float* __restrict__ fcW,
                                               const float* __restrict__ fcb,
                                               float* __restrict__ gout,
                                               float* __restrict__ lout) {
    __shared__ float sp[256 * 4];
    int t = threadIdx.x;
    if (t < 192) {
        unsigned int enc = menc[t];
        unsigned int b = (enc & 0x80000000u) ? (enc & 0x7fffffffu) : ~enc;
        gout[t] = __uint_as_float(b);
    }
    int tn = *target;
    float e = (t < 192) ? emb[(size_t)tn * 192 + t] : 0.0f;
    #pragma unroll
    for (int c = 0; c < 4; ++c)
        sp[t * 4 + c] = (t < 192) ? e * fcW[t * 4 + c] : 0.0f;
    __syncthreads();
    for (int o = 128; o > 0; o >>= 1) {
        if (t < o) {
            #pragma unroll
            for (int c = 0; c < 4; ++c) sp[t * 4 + c] += sp[(t + o) * 4 + c];
        }
        __syncthreads();
    }
    if (t < 4) lout[t] = sp[t] + fcb[t];
}

extern "C" void kernel_launch(void* const* d_in, const int* in_sizes, int n_in,
                              void* d_out, int out_size, void* d_ws, size_t ws_size,
                              hipStream_t stream) {
    const float* x      = (const float*)d_in[0];
    const int* eidx     = (const int*)d_in[1];
    const int* target   = (const int*)d_in[3];
    const float* W1     = (const float*)d_in[4];
    const float* b1     = (const float*)d_in[5];
    const float* W2     = (const float*)d_in[6];
    const float* b2     = (const float*)d_in[7];
    const float* W3     = (const float*)d_in[8];
    const float* b3     = (const float*)d_in[9];
    const float* fcW    = (const float*)d_in[10];
    const float* fcb    = (const float*)d_in[11];
    float* out          = (float*)d_out;

    const int N = in_sizes[0] / 64;
    const int E = in_sizes[1] / 2;
    const int* esrc = eidx;
    const int* edst = eidx + E;

    char* p = (char*)d_ws;
    auto alloc = [&](size_t bytes) -> void* {
        void* r = (void*)p;
        p += (bytes + 255) & ~(size_t)255;
        return r;
    };
    float* dinv          = (float*)alloc((size_t)N * 4);
    int* cnt             = (int*)alloc((size_t)N * 4);       // cnt then menc: one memset
    unsigned int* menc   = (unsigned int*)alloc(192 * 4);
    unsigned short* col  = (unsigned short*)alloc((size_t)N * ELL_CAP * 2);  // 6.4 MB
    unsigned short* g    = (unsigned short*)alloc((size_t)N * 64 * 2);       // 6.4 MB

    size_t cntPad = (((size_t)N * 4) + 255) & ~(size_t)255;
    hipMemsetAsync(cnt, 0, cntPad + 192 * 4, stream);  // zeroes cnt + pad + menc

    int FB = (E + 2047) / 2048;      // fill blocks, 8 edges/thread
    int GB = (N + 63) / 64;          // gemm blocks
    k_fill_gemm1<<<FB + GB, 256, 0, stream>>>(esrc, edst, cnt, col, E, FB,
                                              x, W1, g, N);
    k_scale<<<(N * 16 + 255) / 256, 256, 0, stream>>>(cnt, dinv, g, N);

    int ab = (N * 16 + 255) / 256;   // 16 lanes/node
    // layer 1
    k_aggregate<<<ab, 256, 0, stream>>>(g, dinv, cnt, col, b1, out + 0, 1, N);
    // layer 2 (input = x1 = out[:,0:64], stride 192)
    k_gemm_g<<<GB, 256, 0, stream>>>(out + 0, 192, W2, dinv, g, N);
    k_aggregate<<<ab, 256, 0, stream>>>(g, dinv, cnt, col, b2, out + 64, 1, N);
    // layer 3 (input = x2 = out[:,64:128]), no relu
    k_gemm_g<<<GB, 256, 0, stream>>>(out + 64, 192, W3, dinv, g, N);
    k_aggregate<<<ab, 256, 0, stream>>>(g, dinv, cnt, col, b3, out + 128, 0, N);

    k_colmax<<<512, 192, 0, stream>>>(out, menc, N);
    k_final<<<1, 256, 0, stream>>>(menc, out, target, fcW, fcb,
                                   out + (size_t)N * 192,
                                   out + (size_t)N * 192 + 192);
}

// Round 2
// 304.929 us; speedup vs baseline: 1.9978x; 1.9978x over previous
//
#include <hip/hip_runtime.h>
#include <hip/hip_bf16.h>

// GCN: x1=relu(prop(x W1)), x2=relu(prop(x1 W2)), x3=prop(x2 W3)
// out(fp32) = [emb (N x 192), colmax(emb) (192), emb[target] @ fcW + fcb (4)]
// R8 (base=R7):
//  - REVERT __launch_bounds__(256,4) on k_fill_gemm1: compiler clamped to 64
//    VGPR and spilled the gemm role (FETCH 9.6->449MB scratch traffic, 72->369us).
//    Natural allocation (248 VGPR) is correct for the fused kernel.
//  - KEEP: 8 independent atomic chains/thread in fill role
//  - KEEP: 16-lane/node ushort4 aggregate (saved ~40us vs 64-lane/node in R7)

#define ELL_CAP 64

__device__ __forceinline__ float bfu(unsigned short s) {
    return __uint_as_float(((unsigned)s) << 16);
}
__device__ __forceinline__ unsigned short f2bfu(float f) {
    __hip_bfloat16 b = __float2bfloat16(f);
    return *reinterpret_cast<unsigned short*>(&b);
}

// ---- fused: ELL fill (blocks [0,FB)) + gemm1 g=x@W1 (blocks [FB,FB+GB)) ---
__global__ __launch_bounds__(256) void k_fill_gemm1(
    const int* __restrict__ src, const int* __restrict__ dst,
    int* __restrict__ cnt, unsigned short* __restrict__ col, int E, int FB,
    const float* __restrict__ X, const float* __restrict__ W,
    unsigned short* __restrict__ g, int N) {
    int t = threadIdx.x;
    if ((int)blockIdx.x < FB) {
        // ---- fill role: 8 edges per thread, independent chains ----
        int e0 = blockIdx.x * 2048 + t;
        #pragma unroll
        for (int i = 0; i < 8; ++i) {
            int e = e0 + i * 256;
            if (e < E) {
                int d = dst[e];
                int s = src[e];
                int slot = atomicAdd(&cnt[d], 1);
                if (slot < ELL_CAP) col[((size_t)d << 6) + slot] = (unsigned short)s;
            }
        }
        return;
    }
    // ---- gemm role: 64x64 tile, g = bf16(x @ W1)  (no dinv yet) ----
    __shared__ float Xs[64 * 68];
    __shared__ float Ws[64 * 68];
    int row0 = (blockIdx.x - FB) * 64;
    #pragma unroll
    for (int i = 0; i < 4; ++i) {
        int f = t + i * 256;
        int k = f >> 4, cq = (f & 15) << 2;
        float4 wv = *(const float4*)(W + k * 64 + cq);
        Ws[k * 68 + cq + 0] = wv.x;
        Ws[k * 68 + cq + 1] = wv.y;
        Ws[k * 68 + cq + 2] = wv.z;
        Ws[k * 68 + cq + 3] = wv.w;
        int r = f >> 4, kq = (f & 15) << 2;
        int row = row0 + r;
        float4 xv = make_float4(0.f, 0.f, 0.f, 0.f);
        if (row < N) xv = *(const float4*)(X + (size_t)row * 64 + kq);
        Xs[(kq + 0) * 68 + r] = xv.x;
        Xs[(kq + 1) * 68 + r] = xv.y;
        Xs[(kq + 2) * 68 + r] = xv.z;
        Xs[(kq + 3) * 68 + r] = xv.w;
    }
    __syncthreads();
    int tx = t & 15, ty = t >> 4;
    float acc[4][4] = {};
    #pragma unroll
    for (int k = 0; k < 64; ++k) {
        float4 a = *(const float4*)&Xs[k * 68 + ty * 4];
        float4 b = *(const float4*)&Ws[k * 68 + tx * 4];
        float av[4] = {a.x, a.y, a.z, a.w};
        float bv[4] = {b.x, b.y, b.z, b.w};
        #pragma unroll
        for (int i = 0; i < 4; ++i)
            #pragma unroll
            for (int j = 0; j < 4; ++j) acc[i][j] += av[i] * bv[j];
    }
    #pragma unroll
    for (int i = 0; i < 4; ++i) {
        int row = row0 + ty * 4 + i;
        if (row < N) {
            ushort4 o;
            o.x = f2bfu(acc[i][0]);
            o.y = f2bfu(acc[i][1]);
            o.z = f2bfu(acc[i][2]);
            o.w = f2bfu(acc[i][3]);
            *(ushort4*)(g + (size_t)row * 64 + tx * 4) = o;
        }
    }
}

// ---- scale: dinv[r] = rsqrt(cnt+1); g[r][:] *= dinv[r] --------------------
__global__ __launch_bounds__(256) void k_scale(const int* __restrict__ cnt,
                                               float* __restrict__ dinv,
                                               unsigned short* __restrict__ g, int N) {
    int idx = blockIdx.x * blockDim.x + threadIdx.x;  // one ushort4 (4 chans)
    if (idx >= N * 16) return;
    int r = idx >> 4;
    float d = rsqrtf((float)(cnt[r] + 1));  // +1 self-loop
    if ((idx & 15) == 0) dinv[r] = d;
    ushort4 v = *(ushort4*)(g + (size_t)idx * 4);
    v.x = f2bfu(bfu(v.x) * d);
    v.y = f2bfu(bfu(v.y) * d);
    v.z = f2bfu(bfu(v.z) * d);
    v.w = f2bfu(bfu(v.w) * d);
    *(ushort4*)(g + (size_t)idx * 4) = v;
}

// ---- g = bf16(dinv * (X @ W)); layers 2,3 (X fp32, row stride xstride) ----
__global__ __launch_bounds__(256) void k_gemm_g(const float* __restrict__ X,
                                                int xstride,
                                                const float* __restrict__ W,
                                                const float* __restrict__ dinv,
                                                unsigned short* __restrict__ g, int N) {
    __shared__ float Xs[64 * 68];
    __shared__ float Ws[64 * 68];
    int t = threadIdx.x;
    int row0 = blockIdx.x * 64;
    #pragma unroll
    for (int i = 0; i < 4; ++i) {
        int f = t + i * 256;
        int k = f >> 4, cq = (f & 15) << 2;
        float4 wv = *(const float4*)(W + k * 64 + cq);
        Ws[k * 68 + cq + 0] = wv.x;
        Ws[k * 68 + cq + 1] = wv.y;
        Ws[k * 68 + cq + 2] = wv.z;
        Ws[k * 68 + cq + 3] = wv.w;
        int r = f >> 4, kq = (f & 15) << 2;
        int row = row0 + r;
        float4 xv = make_float4(0.f, 0.f, 0.f, 0.f);
        if (row < N) xv = *(const float4*)(X + (size_t)row * xstride + kq);
        Xs[(kq + 0) * 68 + r] = xv.x;
        Xs[(kq + 1) * 68 + r] = xv.y;
        Xs[(kq + 2) * 68 + r] = xv.z;
        Xs[(kq + 3) * 68 + r] = xv.w;
    }
    __syncthreads();
    int tx = t & 15, ty = t >> 4;
    float acc[4][4] = {};
    #pragma unroll
    for (int k = 0; k < 64; ++k) {
        float4 a = *(const float4*)&Xs[k * 68 + ty * 4];
        float4 b = *(const float4*)&Ws[k * 68 + tx * 4];
        float av[4] = {a.x, a.y, a.z, a.w};
        float bv[4] = {b.x, b.y, b.z, b.w};
        #pragma unroll
        for (int i = 0; i < 4; ++i)
            #pragma unroll
            for (int j = 0; j < 4; ++j) acc[i][j] += av[i] * bv[j];
    }
    #pragma unroll
    for (int i = 0; i < 4; ++i) {
        int row = row0 + ty * 4 + i;
        if (row < N) {
            float dv = dinv[row];
            ushort4 o;
            o.x = f2bfu(acc[i][0] * dv);
            o.y = f2bfu(acc[i][1] * dv);
            o.z = f2bfu(acc[i][2] * dv);
            o.w = f2bfu(acc[i][3] * dv);
            *(ushort4*)(g + (size_t)row * 64 + tx * 4) = o;
        }
    }
}

// 16 lanes per node, each lane owns 4 channels (ushort4 = 8B loads).
// One wave = 4 nodes -> each gather instruction covers 4 edges.
__global__ __launch_bounds__(256) void k_aggregate(
    const unsigned short* __restrict__ g, const float* __restrict__ dinv,
    const int* __restrict__ cnt, const unsigned short* __restrict__ col,
    const float* __restrict__ bias,
    float* __restrict__ outp, int relu, int N) {
    int gid = blockIdx.x * blockDim.x + threadIdx.x;
    int node = gid >> 4;
    int l = gid & 15;           // channels 4l .. 4l+3
    if (node >= N) return;
    ushort4 sv = *(const ushort4*)(g + ((size_t)node << 6) + (l << 2));
    float a0 = bfu(sv.x), a1 = bfu(sv.y), a2 = bfu(sv.z), a3 = bfu(sv.w);
    int deg = cnt[node];
    int m = deg < ELL_CAP ? deg : ELL_CAP;
    const unsigned short* crow = col + ((size_t)node << 6);
    int e = 0;
    for (; e + 3 < m; e += 4) {
        ushort4 s4 = *(const ushort4*)(crow + e);   // uniform in 16-group -> bcast
        ushort4 v0 = *(const ushort4*)(g + ((size_t)s4.x << 6) + (l << 2));
        ushort4 v1 = *(const ushort4*)(g + ((size_t)s4.y << 6) + (l << 2));
        ushort4 v2 = *(const ushort4*)(g + ((size_t)s4.z << 6) + (l << 2));
        ushort4 v3 = *(const ushort4*)(g + ((size_t)s4.w << 6) + (l << 2));
        a0 += (bfu(v0.x) + bfu(v1.x)) + (bfu(v2.x) + bfu(v3.x));
        a1 += (bfu(v0.y) + bfu(v1.y)) + (bfu(v2.y) + bfu(v3.y));
        a2 += (bfu(v0.z) + bfu(v1.z)) + (bfu(v2.z) + bfu(v3.z));
        a3 += (bfu(v0.w) + bfu(v1.w)) + (bfu(v2.w) + bfu(v3.w));
    }
    for (; e < m; ++e) {
        int s = crow[e];
        ushort4 v = *(const ushort4*)(g + ((size_t)s << 6) + (l << 2));
        a0 += bfu(v.x);
        a1 += bfu(v.y);
        a2 += bfu(v.z);
        a3 += bfu(v.w);
    }
    float d = dinv[node];
    float4 bv = *(const float4*)(bias + (l << 2));
    float4 o;
    o.x = fmaf(d, a0, bv.x);
    o.y = fmaf(d, a1, bv.y);
    o.z = fmaf(d, a2, bv.z);
    o.w = fmaf(d, a3, bv.w);
    if (relu) {
        o.x = fmaxf(o.x, 0.0f);
        o.y = fmaxf(o.y, 0.0f);
        o.z = fmaxf(o.z, 0.0f);
        o.w = fmaxf(o.w, 0.0f);
    }
    *(float4*)(outp + (size_t)node * 192 + (l << 2)) = o;
}

// ---- epilogue -------------------------------------------------------------
__global__ __launch_bounds__(192) void k_colmax(const float* __restrict__ emb,
                                                unsigned int* __restrict__ menc, int N) {
    int c = threadIdx.x;
    float m = -3.4e38f;
    for (int r = blockIdx.x; r < N; r += gridDim.x)
        m = fmaxf(m, emb[(size_t)r * 192 + c]);
    unsigned int b = __float_as_uint(m);
    unsigned int enc = (b & 0x80000000u) ? ~b : (b | 0x80000000u);
    atomicMax(&menc[c], enc);
}

__global__ __launch_bounds__(256) void k_final(const unsigned int* __restrict__ menc,
                                               const float* __restrict__ emb,
                                               const int* __restrict__ target,
                                               const float* __restrict__ fcW,
                                               const float* __restrict__ fcb,
                                               float* __restrict__ gout,
                                               float* __restrict__ lout) {
    __shared__ float sp[256 * 4];
    int t = threadIdx.x;
    if (t < 192) {
        unsigned int enc = menc[t];
        unsigned int b = (enc & 0x80000000u) ? (enc & 0x7fffffffu) : ~enc;
        gout[t] = __uint_as_float(b);
    }
    int tn = *target;
    float e = (t < 192) ? emb[(size_t)tn * 192 + t] : 0.0f;
    #pragma unroll
    for (int c = 0; c < 4; ++c)
        sp[t * 4 + c] = (t < 192) ? e * fcW[t * 4 + c] : 0.0f;
    __syncthreads();
    for (int o = 128; o > 0; o >>= 1) {
        if (t < o) {
            #pragma unroll
            for (int c = 0; c < 4; ++c) sp[t * 4 + c] += sp[(t + o) * 4 + c];
        }
        __syncthreads();
    }
    if (t < 4) lout[t] = sp[t] + fcb[t];
}

extern "C" void kernel_launch(void* const* d_in, const int* in_sizes, int n_in,
                              void* d_out, int out_size, void* d_ws, size_t ws_size,
                              hipStream_t stream) {
    const float* x      = (const float*)d_in[0];
    const int* eidx     = (const int*)d_in[1];
    const int* target   = (const int*)d_in[3];
    const float* W1     = (const float*)d_in[4];
    const float* b1     = (const float*)d_in[5];
    const float* W2     = (const float*)d_in[6];
    const float* b2     = (const float*)d_in[7];
    const float* W3     = (const float*)d_in[8];
    const float* b3     = (const float*)d_in[9];
    const float* fcW    = (const float*)d_in[10];
    const float* fcb    = (const float*)d_in[11];
    float* out          = (float*)d_out;

    const int N = in_sizes[0] / 64;
    const int E = in_sizes[1] / 2;
    const int* esrc = eidx;
    const int* edst = eidx + E;

    char* p = (char*)d_ws;
    auto alloc = [&](size_t bytes) -> void* {
        void* r = (void*)p;
        p += (bytes + 255) & ~(size_t)255;
        return r;
    };
    float* dinv          = (float*)alloc((size_t)N * 4);
    int* cnt             = (int*)alloc((size_t)N * 4);       // cnt then menc: one memset
    unsigned int* menc   = (unsigned int*)alloc(192 * 4);
    unsigned short* col  = (unsigned short*)alloc((size_t)N * ELL_CAP * 2);  // 6.4 MB
    unsigned short* g    = (unsigned short*)alloc((size_t)N * 64 * 2);       // 6.4 MB

    size_t cntPad = (((size_t)N * 4) + 255) & ~(size_t)255;
    hipMemsetAsync(cnt, 0, cntPad + 192 * 4, stream);  // zeroes cnt + pad + menc

    int FB = (E + 2047) / 2048;      // fill blocks, 8 edges/thread
    int GB = (N + 63) / 64;          // gemm blocks
    k_fill_gemm1<<<FB + GB, 256, 0, stream>>>(esrc, edst, cnt, col, E, FB,
                                              x, W1, g, N);
    k_scale<<<(N * 16 + 255) / 256, 256, 0, stream>>>(cnt, dinv, g, N);

    int ab = (N * 16 + 255) / 256;   // 16 lanes/node
    // layer 1
    k_aggregate<<<ab, 256, 0, stream>>>(g, dinv, cnt, col, b1, out + 0, 1, N);
    // layer 2 (input = x1 = out[:,0:64], stride 192)
    k_gemm_g<<<GB, 256, 0, stream>>>(out + 0, 192, W2, dinv, g, N);
    k_aggregate<<<ab, 256, 0, stream>>>(g, dinv, cnt, col, b2, out + 64, 1, N);
    // layer 3 (input = x2 = out[:,64:128]), no relu
    k_gemm_g<<<GB, 256, 0, stream>>>(out + 64, 192, W3, dinv, g, N);
    k_aggregate<<<ab, 256, 0, stream>>>(g, dinv, cnt, col, b3, out + 128, 0, N);

    k_colmax<<<512, 192, 0, stream>>>(out, menc, N);
    k_final<<<1, 256, 0, stream>>>(menc, out, target, fcW, fcb,
                                   out + (size_t)N * 192,
                                   out + (size_t)N * 192 + 192);
}